// Round 1
// baseline (1411.578 us; speedup 1.0000x reference)
//
#include <hip/hip_runtime.h>
#include <hip/hip_bf16.h>

// FSMNSeleNetV3: 5 FSMN units + final expand/maxpool/decode.
// Shapes: B=32, T=2048, C=4, F=120, Dl=128, Dp=64, L=5, lorder=10, rorder=1, S=5.
// Sequences: s = b*4 + c (128 sequences of length 2048).
//
// Round 0: correct fp32 baseline.
//   unit_gemm<DIN,IS_X>: z = relu(in @ We + be) @ Ws       (fused expand+shrink)
//   fsmn_k:              y = [res?] + z + causal10(z) + 1-lookahead(z)
//   final_k:             out = (max_c relu(h @ We2 + be2)) @ Wd + bd
// Workspace: H (67.1MB) + Z (67.1MB) = 128 MiB of d_ws.

#define SEQS 128
#define TLEN 2048

template <int DIN, bool IS_X>
__global__ __launch_bounds__(256) void unit_gemm(
    const float* __restrict__ in, const float* __restrict__ We,
    const float* __restrict__ be, const float* __restrict__ Ws,
    float* __restrict__ Z)
{
    // block: 64 time rows of one sequence. gridDim = (32, 128).
    constexpr int XSTR = (DIN == 120) ? 120 : 68;  // both 16B-aligned strides
    __shared__ float Xl[64][XSTR];
    __shared__ float El[64][132];

    const int tid = threadIdx.x;
    const int s   = blockIdx.y;
    const int t0  = blockIdx.x * 64;

    // ---- phase 1: load 64 x DIN input tile (float4, coalesced) ----
    constexpr int NV4 = DIN / 4;  // 30 or 16
    for (int i = tid; i < 64 * NV4; i += 256) {
        int r  = i / NV4;
        int f4 = i - r * NV4;
        long base4;
        if (IS_X) {
            int b = s >> 2, c = s & 3, t = t0 + r;
            base4 = ((long)(b * TLEN + t) * 4 + c) * 30;  // x[b,t,c,:]/4
        } else {
            base4 = (long)(s * TLEN + (t0 + r)) * 16;     // H[s,t,:]/4
        }
        float4 v = reinterpret_cast<const float4*>(in)[base4 + f4];
        *reinterpret_cast<float4*>(&Xl[r][f4 * 4]) = v;
    }
    __syncthreads();

    // ---- phase 2: E = relu(X @ We + be)  [64][128] ----
    {
        const int c0 = tid & 31;   // j = 4*c0 .. 4*c0+3
        const int rg = tid >> 5;   // rows rg*8 .. rg*8+7
        float acc[8][4];
#pragma unroll
        for (int rr = 0; rr < 8; ++rr)
#pragma unroll
            for (int q = 0; q < 4; ++q) acc[rr][q] = 0.f;

        for (int f = 0; f < DIN; ++f) {
            float4 w = reinterpret_cast<const float4*>(We)[f * 32 + c0];
#pragma unroll
            for (int rr = 0; rr < 8; ++rr) {
                float xv = Xl[rg * 8 + rr][f];  // broadcast within wave
                acc[rr][0] += xv * w.x;
                acc[rr][1] += xv * w.y;
                acc[rr][2] += xv * w.z;
                acc[rr][3] += xv * w.w;
            }
        }
        float4 bb = reinterpret_cast<const float4*>(be)[c0];
#pragma unroll
        for (int rr = 0; rr < 8; ++rr) {
            float4 e;
            e.x = fmaxf(acc[rr][0] + bb.x, 0.f);
            e.y = fmaxf(acc[rr][1] + bb.y, 0.f);
            e.z = fmaxf(acc[rr][2] + bb.z, 0.f);
            e.w = fmaxf(acc[rr][3] + bb.w, 0.f);
            *reinterpret_cast<float4*>(&El[rg * 8 + rr][c0 * 4]) = e;
        }
    }
    __syncthreads();

    // ---- phase 3: O = E @ Ws  [64][64] -> Z ----
    {
        const int d0 = tid & 15;   // d = 4*d0 .. 4*d0+3
        const int rg = tid >> 4;   // rows rg*4 .. rg*4+3
        float acc[4][4];
#pragma unroll
        for (int rr = 0; rr < 4; ++rr)
#pragma unroll
            for (int q = 0; q < 4; ++q) acc[rr][q] = 0.f;

        for (int j = 0; j < 128; ++j) {
            float4 w = reinterpret_cast<const float4*>(Ws)[j * 16 + d0];
#pragma unroll
            for (int rr = 0; rr < 4; ++rr) {
                float ev = El[rg * 4 + rr][j];  // broadcast/2-way
                acc[rr][0] += ev * w.x;
                acc[rr][1] += ev * w.y;
                acc[rr][2] += ev * w.z;
                acc[rr][3] += ev * w.w;
            }
        }
#pragma unroll
        for (int rr = 0; rr < 4; ++rr) {
            int t = t0 + rg * 4 + rr;
            float4 o = make_float4(acc[rr][0], acc[rr][1], acc[rr][2], acc[rr][3]);
            reinterpret_cast<float4*>(Z)[(long)(s * TLEN + t) * 16 + d0] = o;
        }
    }
}

// y[s,t,d] = (res ? Hin : 0) + z[t] + sum_{k=0..9} wl[k,d]*z[t+k-9] + wr[d]*z[t+1]
__global__ __launch_bounds__(256) void fsmn_k(
    const float* __restrict__ Zin, const float* __restrict__ Hin,
    float* __restrict__ Y, const float* __restrict__ wl,
    const float* __restrict__ wr, int has_res)
{
    int idx = blockIdx.x * 256 + threadIdx.x;  // < 128*2048*64
    int d = idx & 63;
    int t = (idx >> 6) & (TLEN - 1);
    float acc = Zin[idx];
#pragma unroll
    for (int k = 0; k < 10; ++k) {
        int tt = t + k - 9;
        if (tt >= 0) acc += wl[k * 64 + d] * Zin[idx + (k - 9) * 64];
    }
    if (t < TLEN - 1) acc += wr[d] * Zin[idx + 64];
    if (has_res) acc += Hin[idx];
    Y[idx] = acc;
}

// out[b,t,:] = (max_c relu(H[b,c,t,:] @ We2 + be2)) @ Wd + bd
__global__ __launch_bounds__(256) void final_k(
    const float* __restrict__ H, const float* __restrict__ We2,
    const float* __restrict__ be2, const float* __restrict__ Wd,
    const float* __restrict__ bd, float* __restrict__ out)
{
    __shared__ float Hl[16][4][64];
    __shared__ float Ml[16][132];
    const int tid = threadIdx.x;
    const int bt0 = blockIdx.x * 16;

    // load 16 (b,t) rows x 4 channels x 64
    for (int i = tid; i < 16 * 64; i += 256) {
        int r = i >> 6;
        int rem = i & 63;
        int c = rem >> 4;
        int d4 = rem & 15;
        int bt = bt0 + r;
        int b = bt >> 11;
        int t = bt & (TLEN - 1);
        float4 v = reinterpret_cast<const float4*>(H)[(long)((b * 4 + c) * TLEN + t) * 16 + d4];
        *reinterpret_cast<float4*>(&Hl[r][c][d4 * 4]) = v;
    }
    __syncthreads();

    // phase A: m[r][j] = max_c relu(sum_d Hl[r][c][d]*We2[d][j] + be2[j])
    {
        const int j4 = tid & 31;  // j = 4*j4 ..
        const int rg = tid >> 5;  // rows rg*2, rg*2+1
        float acc[2][4][4];
#pragma unroll
        for (int rr = 0; rr < 2; ++rr)
#pragma unroll
            for (int cc = 0; cc < 4; ++cc)
#pragma unroll
                for (int q = 0; q < 4; ++q) acc[rr][cc][q] = 0.f;

        for (int d = 0; d < 64; ++d) {
            float4 w = reinterpret_cast<const float4*>(We2)[d * 32 + j4];
#pragma unroll
            for (int rr = 0; rr < 2; ++rr)
#pragma unroll
                for (int cc = 0; cc < 4; ++cc) {
                    float xv = Hl[rg * 2 + rr][cc][d];
                    acc[rr][cc][0] += xv * w.x;
                    acc[rr][cc][1] += xv * w.y;
                    acc[rr][cc][2] += xv * w.z;
                    acc[rr][cc][3] += xv * w.w;
                }
        }
        float4 bb = reinterpret_cast<const float4*>(be2)[j4];
#pragma unroll
        for (int rr = 0; rr < 2; ++rr) {
            float4 m;
            m.x = fmaxf(fmaxf(fmaxf(acc[rr][0][0], acc[rr][1][0]),
                              fmaxf(acc[rr][2][0], acc[rr][3][0])) + bb.x, 0.f);
            m.y = fmaxf(fmaxf(fmaxf(acc[rr][0][1], acc[rr][1][1]),
                              fmaxf(acc[rr][2][1], acc[rr][3][1])) + bb.y, 0.f);
            m.z = fmaxf(fmaxf(fmaxf(acc[rr][0][2], acc[rr][1][2]),
                              fmaxf(acc[rr][2][2], acc[rr][3][2])) + bb.z, 0.f);
            m.w = fmaxf(fmaxf(fmaxf(acc[rr][0][3], acc[rr][1][3]),
                              fmaxf(acc[rr][2][3], acc[rr][3][3])) + bb.w, 0.f);
            // NOTE: max_c(relu(a_c + b)) == relu(max_c(a_c) + b) since relu monotone
            *reinterpret_cast<float4*>(&Ml[rg * 2 + rr][j4 * 4]) = m;
        }
    }
    __syncthreads();

    // phase B: out[r][q] = Ml[r][:] @ Wd[:,q] + bd[q]
    if (tid < 80) {
        int r = tid / 5, q = tid - r * 5;
        float acc = bd[q];
        for (int j = 0; j < 128; ++j) acc += Ml[r][j] * Wd[j * 5 + q];
        out[(long)(bt0 + r) * 5 + q] = acc;
    }
}

extern "C" void kernel_launch(void* const* d_in, const int* in_sizes, int n_in,
                              void* d_out, int out_size, void* d_ws, size_t ws_size,
                              hipStream_t stream) {
    const float* x   = (const float*)d_in[0];
    const float* We0 = (const float*)d_in[1];
    const float* be0 = (const float*)d_in[2];
    const float* Ws0 = (const float*)d_in[3];
    const float* wl0 = (const float*)d_in[4];
    const float* wr0 = (const float*)d_in[5];
    const float* We  = (const float*)d_in[6];
    const float* be  = (const float*)d_in[7];
    const float* Ws  = (const float*)d_in[8];
    const float* wl  = (const float*)d_in[9];
    const float* wr  = (const float*)d_in[10];
    const float* We2 = (const float*)d_in[11];
    const float* be2 = (const float*)d_in[12];
    const float* Wd  = (const float*)d_in[13];
    const float* bd  = (const float*)d_in[14];

    float* H = (float*)d_ws;                          // [128,2048,64]
    float* Z = H + (size_t)SEQS * TLEN * 64;          // [128,2048,64]

    dim3 gA(TLEN / 64, SEQS);
    const int elems = SEQS * TLEN * 64;               // 16.7M
    const int gF = elems / 256;                       // 65536

    // unit 0 (DIN=120, reads x with transpose indexing, no residual)
    unit_gemm<120, true><<<gA, 256, 0, stream>>>(x, We0, be0, Ws0, Z);
    fsmn_k<<<gF, 256, 0, stream>>>(Z, nullptr, H, wl0, wr0, 0);

    // units 1..4 (DIN=64, residual, fsmn writes H in-place: each thread only
    // reads Hin at its own output index)
    for (int l = 0; l < 4; ++l) {
        unit_gemm<64, false><<<gA, 256, 0, stream>>>(
            H, We + (size_t)l * 64 * 128, be + (size_t)l * 128,
            Ws + (size_t)l * 128 * 64, Z);
        fsmn_k<<<gF, 256, 0, stream>>>(Z, H, H, wl + (size_t)l * 10 * 64,
                                       wr + (size_t)l * 64, 1);
    }

    // final: expand+relu, max over channels, decode
    final_k<<<(32 * TLEN) / 16, 256, 0, stream>>>(H, We2, be2, Wd, bd,
                                                  (float*)d_out);
}

// Round 2
// 348.148 us; speedup vs baseline: 4.0545x; 4.0545x over previous
//
#include <hip/hip_runtime.h>
#include <hip/hip_bf16.h>

// FSMNSeleNetV3 — round 2: bf16-MFMA fused unit kernel.
// Per unit: H_in -> [stage 80 rows bf16 LDS, XOR-swizzled]
//           -> expand (MFMA 16x16x32, relu, bias) -> E (LDS bf16, swizzled)
//           -> shrink (MFMA) -> Z (LDS f32, stride 68)
//           -> FSMN epilogue (11-tap sliding window) + residual -> H_out (f32).
// Ping-pong H0/H1 (2 x 67.1 MB = all of d_ws). Transposed bf16 weights are
// prepared once per launch into the head of d_out (scratch; final_k overwrites
// every d_out element afterwards, so validation sees only the real output).
// Accuracy budget: bf16 on GEMM inputs only; accum/bias/FSMN/residual/H = f32.

#define TLEN 2048
#define SEQS 128

typedef __attribute__((ext_vector_type(8))) short bf16x8;
typedef __attribute__((ext_vector_type(4))) float f32x4;

__device__ __forceinline__ ushort f2b(float f) {
    unsigned u = __builtin_bit_cast(unsigned, f);
    return (ushort)((u + 0x7fffu + ((u >> 16) & 1u)) >> 16);  // RNE
}

// ---- weight prep: f32 -> bf16, transposed to [n][k] ----
// wbuf layout (ushort):
//   WeT0 [128][128] @ 0       (k>=120 zero-padded)
//   WsT0 [64][128]  @ 16384
//   l=0..3: WeTl [128][64] @ 24576+l*16384 ; WsTl [64][128] @ +8192
__global__ __launch_bounds__(256) void prep_k(
    const float* __restrict__ We0, const float* __restrict__ Ws0,
    const float* __restrict__ We,  const float* __restrict__ Ws,
    ushort* __restrict__ wbuf)
{
    int idx = blockIdx.x * 256 + threadIdx.x;  // < 90112
    float v;
    if (idx < 16384) {
        int n = idx >> 7, k = idx & 127;
        v = (k < 120) ? We0[k * 128 + n] : 0.f;
    } else if (idx < 24576) {
        int i = idx - 16384;
        int n = i >> 7, k = i & 127;
        v = Ws0[k * 64 + n];
    } else {
        int i = idx - 24576;
        int l = i >> 14, j = i & 16383;
        if (j < 8192) { int n = j >> 6,  k = j & 63;  v = We[l * 8192 + k * 128 + n]; }
        else          { int j2 = j - 8192; int n = j2 >> 7, k = j2 & 127; v = Ws[l * 8192 + k * 64 + n]; }
    }
    wbuf[idx] = f2b(v);
}

// ---- fused unit kernel ----
// Block: 64 output rows (t0..t0+63) of sequence s; stages rows t0-10..t0+69.
template <int KDIM, bool X0, bool HAS_RES>
__global__ __launch_bounds__(256) void unit_fused(
    const float* __restrict__ in, const float* __restrict__ res,
    const ushort* __restrict__ WeT, const float* __restrict__ be,
    const ushort* __restrict__ WsT,
    const float* __restrict__ wl, const float* __restrict__ wr,
    float* __restrict__ Hout)
{
    // region 0 (21760 B): smX [80][KDIM] bf16 swizzled, later aliased by
    //                     smZ [80][68] f32 (X dead after expand reads).
    // region 1 (20480 B): smE [80][128] bf16 swizzled.
    __shared__ char smraw[21760 + 20480];
    float* smZ = (float*)smraw;
    char*  smEb = smraw + 21760;

    const int tid = threadIdx.x;
    const int s   = blockIdx.y;
    const int t0  = blockIdx.x * 64;
    const int ln  = tid & 63;
    const int w   = tid >> 6;     // wave id 0..3
    const int lr  = ln & 15;      // fragment row/col lane index
    const int lg  = ln >> 4;      // fragment k-group

    // ---- stage X: 80 rows x KDIM bf16, 16B slots, XOR swizzle ----
    constexpr int SLOTS = KDIM / 8;                 // 16B slots per row
    const int bq = s >> 2, cq = s & 3;              // only used when X0
    for (int i = tid; i < 80 * SLOTS; i += 256) {
        int r = i / SLOTS, s16 = i % SLOTS;
        int t = t0 - 10 + r;
        float4 v0 = make_float4(0.f, 0.f, 0.f, 0.f);
        float4 v1 = v0;
        bool valid = (t >= 0) && (t < TLEN) && (!X0 || s16 < 15);
        if (valid) {
            int fb;
            if (X0) fb = ((bq * TLEN + t) * 4 + cq) * 120 + s16 * 8;
            else    fb = (s * TLEN + t) * 64 + s16 * 8;
            v0 = *reinterpret_cast<const float4*>(in + fb);
            v1 = *reinterpret_cast<const float4*>(in + fb + 4);
        }
        bf16x8 p;
        p[0] = (short)f2b(v0.x); p[1] = (short)f2b(v0.y);
        p[2] = (short)f2b(v0.z); p[3] = (short)f2b(v0.w);
        p[4] = (short)f2b(v1.x); p[5] = (short)f2b(v1.y);
        p[6] = (short)f2b(v1.z); p[7] = (short)f2b(v1.w);
        int off = (r * (KDIM * 2) + s16 * 16) ^ ((r & 7) << 4);
        *reinterpret_cast<bf16x8*>(smraw + off) = p;
    }
    __syncthreads();

    // ---- expand: E[80][128] = relu(X @ We + be), wave w owns cols w*32..+32 ----
    constexpr int KC = KDIM / 32;
    {
        bf16x8 bE[2][KC];
#pragma unroll
        for (int nt = 0; nt < 2; ++nt)
#pragma unroll
            for (int kc = 0; kc < KC; ++kc) {
                int n = w * 32 + nt * 16 + lr;
                bE[nt][kc] = *reinterpret_cast<const bf16x8*>(
                    WeT + n * KDIM + kc * 32 + lg * 8);
            }
        f32x4 accE[5][2];
#pragma unroll
        for (int mt = 0; mt < 5; ++mt)
#pragma unroll
            for (int nt = 0; nt < 2; ++nt) accE[mt][nt] = (f32x4){0.f, 0.f, 0.f, 0.f};

#pragma unroll
        for (int kc = 0; kc < KC; ++kc) {
            bf16x8 a[5];
#pragma unroll
            for (int mt = 0; mt < 5; ++mt) {
                int row = mt * 16 + lr;
                int off = (row * (KDIM * 2) + kc * 64 + lg * 16) ^ ((row & 7) << 4);
                a[mt] = *reinterpret_cast<const bf16x8*>(smraw + off);
            }
#pragma unroll
            for (int mt = 0; mt < 5; ++mt)
#pragma unroll
                for (int nt = 0; nt < 2; ++nt)
                    accE[mt][nt] = __builtin_amdgcn_mfma_f32_16x16x32_bf16(
                        a[mt], bE[nt][kc], accE[mt][nt], 0, 0, 0);
        }
        // bias + relu -> smE (bf16, swizzled)
        float b0 = be[w * 32 + lr];
        float b1 = be[w * 32 + 16 + lr];
#pragma unroll
        for (int mt = 0; mt < 5; ++mt)
#pragma unroll
            for (int q = 0; q < 4; ++q) {
                int row = mt * 16 + lg * 4 + q;
                int swz = (row & 7) << 4;
                float v0 = fmaxf(accE[mt][0][q] + b0, 0.f);
                int col0 = w * 32 + lr;
                *reinterpret_cast<ushort*>(smEb + ((row * 256 + col0 * 2) ^ swz)) = f2b(v0);
                float v1 = fmaxf(accE[mt][1][q] + b1, 0.f);
                int col1 = col0 + 16;
                *reinterpret_cast<ushort*>(smEb + ((row * 256 + col1 * 2) ^ swz)) = f2b(v1);
            }
    }
    __syncthreads();   // all X reads done; smZ (aliasing smX) safe to write

    // ---- shrink: Z[80][64] = E @ Ws, wave w owns cols w*16..+16 ----
    {
        bf16x8 bS[4];
#pragma unroll
        for (int kc = 0; kc < 4; ++kc) {
            int n = w * 16 + lr;
            bS[kc] = *reinterpret_cast<const bf16x8*>(WsT + n * 128 + kc * 32 + lg * 8);
        }
        f32x4 accS[5];
#pragma unroll
        for (int mt = 0; mt < 5; ++mt) accS[mt] = (f32x4){0.f, 0.f, 0.f, 0.f};
#pragma unroll
        for (int kc = 0; kc < 4; ++kc) {
#pragma unroll
            for (int mt = 0; mt < 5; ++mt) {
                int row = mt * 16 + lr;
                int off = (row * 256 + kc * 64 + lg * 16) ^ ((row & 7) << 4);
                bf16x8 a = *reinterpret_cast<const bf16x8*>(smEb + off);
                accS[mt] = __builtin_amdgcn_mfma_f32_16x16x32_bf16(
                    a, bS[kc], accS[mt], 0, 0, 0);
            }
        }
#pragma unroll
        for (int mt = 0; mt < 5; ++mt)
#pragma unroll
            for (int q = 0; q < 4; ++q) {
                int row = mt * 16 + lg * 4 + q;
                int col = w * 16 + lr;
                smZ[row * 68 + col] = accS[mt][q];   // stride 68: conflict-free
            }
    }
    __syncthreads();

    // ---- FSMN epilogue: y[t] = z[t] + sum_k wl[k] z[t-9+k] + wr z[t+1] (+res) ----
    {
        const int d  = tid & 63;
        const int wv = tid >> 6;          // wave handles output rows wv*16..+16
        float wlv[10];
#pragma unroll
        for (int k = 0; k < 10; ++k) wlv[k] = wl[k * 64 + d];
        float wrv = wr[d];

        const int r0 = wv * 16;
        float zwin[11];                   // z[t-9] .. z[t+1] for t = t0+r0
#pragma unroll
        for (int j = 0; j < 11; ++j) {
            int tt = t0 + r0 - 9 + j;
            zwin[j] = (tt >= 0 && tt < TLEN) ? smZ[(r0 + 1 + j) * 68 + d] : 0.f;
        }
#pragma unroll
        for (int i = 0; i < 16; ++i) {
            int ro = r0 + i;
            int t  = t0 + ro;
            float acc = zwin[9];                       // z[t]
#pragma unroll
            for (int k = 0; k < 10; ++k) acc += wlv[k] * zwin[k];
            acc += wrv * zwin[10];
            int gi = (s * TLEN + t) * 64 + d;
            if (HAS_RES) acc += res[gi];
            Hout[gi] = acc;
            if (i < 15) {
#pragma unroll
                for (int j = 0; j < 10; ++j) zwin[j] = zwin[j + 1];
                int tt = t + 2;                        // next row's z[t'+1]
                zwin[10] = (tt < TLEN) ? smZ[(ro + 12) * 68 + d] : 0.f;
            }
        }
    }
}

// ---- final: out[b,t,:] = (max_c relu(H[b,c,t,:] @ We2 + be2)) @ Wd + bd ----
__global__ __launch_bounds__(256) void final_k(
    const float* __restrict__ H, const float* __restrict__ We2,
    const float* __restrict__ be2, const float* __restrict__ Wd,
    const float* __restrict__ bd, float* __restrict__ out)
{
    __shared__ float Hl[16][4][64];
    __shared__ float Ml[16][132];
    const int tid = threadIdx.x;
    const int bt0 = blockIdx.x * 16;

    for (int i = tid; i < 16 * 64; i += 256) {
        int r = i >> 6;
        int rem = i & 63;
        int c = rem >> 4;
        int d4 = rem & 15;
        int bt = bt0 + r;
        int b = bt >> 11;
        int t = bt & (TLEN - 1);
        float4 v = reinterpret_cast<const float4*>(H)[(long)((b * 4 + c) * TLEN + t) * 16 + d4];
        *reinterpret_cast<float4*>(&Hl[r][c][d4 * 4]) = v;
    }
    __syncthreads();

    {
        const int j4 = tid & 31;
        const int rg = tid >> 5;
        float acc[2][4][4];
#pragma unroll
        for (int rr = 0; rr < 2; ++rr)
#pragma unroll
            for (int cc = 0; cc < 4; ++cc)
#pragma unroll
                for (int q = 0; q < 4; ++q) acc[rr][cc][q] = 0.f;

        for (int dd = 0; dd < 64; ++dd) {
            float4 wv = reinterpret_cast<const float4*>(We2)[dd * 32 + j4];
#pragma unroll
            for (int rr = 0; rr < 2; ++rr)
#pragma unroll
                for (int cc = 0; cc < 4; ++cc) {
                    float xv = Hl[rg * 2 + rr][cc][dd];
                    acc[rr][cc][0] += xv * wv.x;
                    acc[rr][cc][1] += xv * wv.y;
                    acc[rr][cc][2] += xv * wv.z;
                    acc[rr][cc][3] += xv * wv.w;
                }
        }
        float4 bb = reinterpret_cast<const float4*>(be2)[j4];
#pragma unroll
        for (int rr = 0; rr < 2; ++rr) {
            float4 m;
            m.x = fmaxf(fmaxf(fmaxf(acc[rr][0][0], acc[rr][1][0]),
                              fmaxf(acc[rr][2][0], acc[rr][3][0])) + bb.x, 0.f);
            m.y = fmaxf(fmaxf(fmaxf(acc[rr][0][1], acc[rr][1][1]),
                              fmaxf(acc[rr][2][1], acc[rr][3][1])) + bb.y, 0.f);
            m.z = fmaxf(fmaxf(fmaxf(acc[rr][0][2], acc[rr][1][2]),
                              fmaxf(acc[rr][2][2], acc[rr][3][2])) + bb.z, 0.f);
            m.w = fmaxf(fmaxf(fmaxf(acc[rr][0][3], acc[rr][1][3]),
                              fmaxf(acc[rr][2][3], acc[rr][3][3])) + bb.w, 0.f);
            *reinterpret_cast<float4*>(&Ml[rg * 2 + rr][j4 * 4]) = m;
        }
    }
    __syncthreads();

    if (tid < 80) {
        int r = tid / 5, q = tid - r * 5;
        float acc = bd[q];
        for (int j = 0; j < 128; ++j) acc += Ml[r][j] * Wd[j * 5 + q];
        out[(long)(bt0 + r) * 5 + q] = acc;
    }
}

extern "C" void kernel_launch(void* const* d_in, const int* in_sizes, int n_in,
                              void* d_out, int out_size, void* d_ws, size_t ws_size,
                              hipStream_t stream) {
    const float* x   = (const float*)d_in[0];
    const float* We0 = (const float*)d_in[1];
    const float* be0 = (const float*)d_in[2];
    const float* Ws0 = (const float*)d_in[3];
    const float* wl0 = (const float*)d_in[4];
    const float* wr0 = (const float*)d_in[5];
    const float* We  = (const float*)d_in[6];
    const float* be  = (const float*)d_in[7];
    const float* Ws  = (const float*)d_in[8];
    const float* wl  = (const float*)d_in[9];
    const float* wr  = (const float*)d_in[10];
    const float* We2 = (const float*)d_in[11];
    const float* be2 = (const float*)d_in[12];
    const float* Wd  = (const float*)d_in[13];
    const float* bd  = (const float*)d_in[14];

    float* H0 = (float*)d_ws;
    float* H1 = H0 + (size_t)SEQS * TLEN * 64;      // d_ws fully used (134.2 MB)
    // weight scratch lives in d_out; final_k overwrites all of d_out afterwards
    ushort* wbuf = (ushort*)d_out;                   // 90112 ushort = 176 KB << 1.31 MB

    prep_k<<<352, 256, 0, stream>>>(We0, Ws0, We, Ws, wbuf);

    dim3 gU(TLEN / 64, SEQS);
    // unit 0: x -> H0
    unit_fused<128, true, false><<<gU, 256, 0, stream>>>(
        x, x, wbuf, be0, wbuf + 16384, wl0, wr0, H0);

    // units 1..4: ping-pong H0 <-> H1 (halo reads forbid in-place)
    const float* cur = H0;
    float* nxt = H1;
    for (int l = 0; l < 4; ++l) {
        const ushort* WeTl = wbuf + 24576 + l * 16384;
        const ushort* WsTl = WeTl + 8192;
        unit_fused<64, false, true><<<gU, 256, 0, stream>>>(
            cur, cur, WeTl, be + l * 128, WsTl, wl + l * 640, wr + l * 64, nxt);
        const float* tmp = cur; cur = nxt; nxt = (float*)tmp;
    }
    // after 4 swaps cur == H0

    final_k<<<(32 * TLEN) / 16, 256, 0, stream>>>(cur, We2, be2, Wd, bd,
                                                  (float*)d_out);
}

// Round 3
// 239.457 us; speedup vs baseline: 5.8949x; 1.4539x over previous
//
#include <hip/hip_runtime.h>
#include <hip/hip_bf16.h>

// FSMNSeleNetV3 — round 3: bf16 H + global_load_lds staging + LDS residual +
// MFMA final kernel.
//   unit_fused: stage 80 rows bf16 (async DMA, src-swizzled) -> expand MFMA ->
//               E (LDS bf16 swz) -> shrink MFMA -> Z (LDS f32) -> FSMN epilogue
//               (residual read from staged LDS, not global) -> H bf16.
//   final_mfma: A-rows = c*16+t so max-over-channel is an elementwise register
//               max over the 4 A-fragments; then 128-dot decode.
// d_ws: H0 (33.5MB) + H1 (33.5MB) + wbuf (196KB transposed bf16 weights).

#define TLEN 2048
#define SEQS 128

typedef __attribute__((ext_vector_type(8))) short bf16x8;
typedef __attribute__((ext_vector_type(4))) float f32x4;

__device__ __forceinline__ ushort f2b(float f) {
    unsigned u = __builtin_bit_cast(unsigned, f);
    return (ushort)((u + 0x7fffu + ((u >> 16) & 1u)) >> 16);  // RNE
}
__device__ __forceinline__ float b2f(ushort u) {
    unsigned v = ((unsigned)u) << 16;
    return __builtin_bit_cast(float, v);
}
__device__ __forceinline__ void gload16(void* lds, const void* g) {
    __builtin_amdgcn_global_load_lds(
        (const __attribute__((address_space(1))) unsigned*)g,
        (__attribute__((address_space(3))) unsigned*)lds, 16, 0, 0);
}

// ---- weight prep: f32 -> bf16, transposed to [n][k] ----
// wbuf layout (ushort):
//   WeT0 [128][128] @0 ; WsT0 [64][128] @16384
//   l=0..3: WeTl [128][64] @24576+l*16384 ; WsTl [64][128] @+8192
//   We2T [128][64] @90112   (total 98304)
__global__ __launch_bounds__(256) void prep_k(
    const float* __restrict__ We0, const float* __restrict__ Ws0,
    const float* __restrict__ We,  const float* __restrict__ Ws,
    const float* __restrict__ We2, ushort* __restrict__ wbuf)
{
    int idx = blockIdx.x * 256 + threadIdx.x;  // grid covers exactly 98304
    float v;
    if (idx < 16384) {
        int n = idx >> 7, k = idx & 127;
        v = (k < 120) ? We0[k * 128 + n] : 0.f;
    } else if (idx < 24576) {
        int i = idx - 16384;
        int n = i >> 7, k = i & 127;
        v = Ws0[k * 64 + n];
    } else if (idx < 90112) {
        int i = idx - 24576;
        int l = i >> 14, j = i & 16383;
        if (j < 8192) { int n = j >> 6, k = j & 63; v = We[l * 8192 + k * 128 + n]; }
        else { int j2 = j - 8192; int n = j2 >> 7, k = j2 & 127; v = Ws[l * 8192 + k * 64 + n]; }
    } else {
        int i = idx - 90112;
        int n = i >> 6, k = i & 63;
        v = We2[k * 128 + n];
    }
    wbuf[idx] = f2b(v);
}

// ---- fused unit kernel: 64 output rows of sequence s, stages rows t0-10..t0+69 ----
template <int KDIM, bool X0, bool HAS_RES>
__global__ __launch_bounds__(256) void unit_fused(
    const void* __restrict__ inv, const ushort* __restrict__ WeT,
    const float* __restrict__ be, const ushort* __restrict__ WsT,
    const float* __restrict__ wl, const float* __restrict__ wr,
    ushort* __restrict__ Hout)
{
    constexpr int XB = 80 * KDIM * 2;          // staged X bytes
    constexpr int ZB = 80 * 68 * 4;            // Z f32, stride 68 (2-way = free)
    constexpr int R0 = HAS_RES ? (XB + ZB) : (ZB > XB ? ZB : XB);  // alias only if no residual
    __shared__ char smraw[R0 + 80 * 256];
    char*  smXb = smraw;
    float* smZ  = (float*)(HAS_RES ? (smraw + XB) : smraw);
    char*  smEb = smraw + R0;

    const int tid = threadIdx.x;
    const int s   = blockIdx.y;
    const int t0  = blockIdx.x * 64;
    const int ln  = tid & 63;
    const int w   = tid >> 6;
    const int lr  = ln & 15;
    const int lg  = ln >> 4;

    // ---- stage X ----
    if constexpr (X0) {
        // f32 x -> bf16 regs -> LDS (KDIM=128, cols 120..127 zero)
        const float* in = (const float*)inv;
        const int bq = s >> 2, cq = s & 3;
        for (int i = tid; i < 80 * 16; i += 256) {
            int r = i >> 4, s16 = i & 15;
            int t = t0 - 10 + r;
            float4 v0 = make_float4(0.f, 0.f, 0.f, 0.f), v1 = v0;
            if (t >= 0 && t < TLEN && s16 < 15) {
                int fb = ((bq * TLEN + t) * 4 + cq) * 120 + s16 * 8;
                v0 = *reinterpret_cast<const float4*>(in + fb);
                v1 = *reinterpret_cast<const float4*>(in + fb + 4);
            }
            bf16x8 p;
            p[0] = (short)f2b(v0.x); p[1] = (short)f2b(v0.y);
            p[2] = (short)f2b(v0.z); p[3] = (short)f2b(v0.w);
            p[4] = (short)f2b(v1.x); p[5] = (short)f2b(v1.y);
            p[6] = (short)f2b(v1.z); p[7] = (short)f2b(v1.w);
            int off = (r * 256 + s16 * 16) ^ ((r & 7) << 4);
            *reinterpret_cast<bf16x8*>(smXb + off) = p;
        }
    } else {
        // bf16 H: async DMA, linear LDS dest + inverse-swizzled global source.
        const ushort* Hin = (const ushort*)inv;
        bf16x8 zv = {0, 0, 0, 0, 0, 0, 0, 0};
        if (t0 == 0)
            for (int i = tid; i < 80; i += 256)               // rows 0..9
                *reinterpret_cast<bf16x8*>(smXb + i * 16) = zv;
        if (t0 == TLEN - 64)
            for (int i = tid; i < 48; i += 256)               // rows 74..79
                *reinterpret_cast<bf16x8*>(smXb + (74 * 8 + i) * 16) = zv;
#pragma unroll
        for (int it = 0; it < 3; ++it) {
            int r0 = it * 32 + w * 8;       // this wave's 8-row group
            if (r0 < 80) {
                int row = r0 + (ln >> 3);
                int t   = t0 - 10 + row;
                int sslot = (ln & 7) ^ (row & 7);
                if (t >= 0 && t < TLEN)
                    gload16(smXb + r0 * 128,
                            Hin + (size_t)(s * TLEN + t) * 64 + sslot * 8);
            }
        }
    }
    __syncthreads();

    // ---- expand: E[80][128] = relu(X @ We + be); wave w: cols w*32..+32 ----
    constexpr int KC = KDIM / 32;
    {
        bf16x8 bE[2][KC];
#pragma unroll
        for (int nt = 0; nt < 2; ++nt)
#pragma unroll
            for (int kc = 0; kc < KC; ++kc) {
                int n = w * 32 + nt * 16 + lr;
                bE[nt][kc] = *reinterpret_cast<const bf16x8*>(
                    WeT + n * KDIM + kc * 32 + lg * 8);
            }
        f32x4 accE[5][2];
#pragma unroll
        for (int mt = 0; mt < 5; ++mt)
#pragma unroll
            for (int nt = 0; nt < 2; ++nt) accE[mt][nt] = (f32x4){0.f, 0.f, 0.f, 0.f};
#pragma unroll
        for (int kc = 0; kc < KC; ++kc) {
            bf16x8 a[5];
#pragma unroll
            for (int mt = 0; mt < 5; ++mt) {
                int row = mt * 16 + lr;
                int off = (row * (KDIM * 2) + kc * 64 + lg * 16) ^ ((row & 7) << 4);
                a[mt] = *reinterpret_cast<const bf16x8*>(smXb + off);
            }
#pragma unroll
            for (int mt = 0; mt < 5; ++mt)
#pragma unroll
                for (int nt = 0; nt < 2; ++nt)
                    accE[mt][nt] = __builtin_amdgcn_mfma_f32_16x16x32_bf16(
                        a[mt], bE[nt][kc], accE[mt][nt], 0, 0, 0);
        }
        float b0 = be[w * 32 + lr];
        float b1 = be[w * 32 + 16 + lr];
#pragma unroll
        for (int mt = 0; mt < 5; ++mt)
#pragma unroll
            for (int q = 0; q < 4; ++q) {
                int row = mt * 16 + lg * 4 + q;
                int swz = (row & 7) << 4;
                int col0 = w * 32 + lr;
                *reinterpret_cast<ushort*>(smEb + ((row * 256 + col0 * 2) ^ swz)) =
                    f2b(fmaxf(accE[mt][0][q] + b0, 0.f));
                *reinterpret_cast<ushort*>(smEb + ((row * 256 + (col0 + 16) * 2) ^ swz)) =
                    f2b(fmaxf(accE[mt][1][q] + b1, 0.f));
            }
    }
    __syncthreads();

    // ---- shrink: Z[80][64] = E @ Ws; wave w: cols w*16..+16 ----
    {
        bf16x8 bS[4];
#pragma unroll
        for (int kc = 0; kc < 4; ++kc) {
            int n = w * 16 + lr;
            bS[kc] = *reinterpret_cast<const bf16x8*>(WsT + n * 128 + kc * 32 + lg * 8);
        }
        f32x4 accS[5];
#pragma unroll
        for (int mt = 0; mt < 5; ++mt) accS[mt] = (f32x4){0.f, 0.f, 0.f, 0.f};
#pragma unroll
        for (int kc = 0; kc < 4; ++kc)
#pragma unroll
            for (int mt = 0; mt < 5; ++mt) {
                int row = mt * 16 + lr;
                int off = (row * 256 + kc * 64 + lg * 16) ^ ((row & 7) << 4);
                bf16x8 a = *reinterpret_cast<const bf16x8*>(smEb + off);
                accS[mt] = __builtin_amdgcn_mfma_f32_16x16x32_bf16(
                    a, bS[kc], accS[mt], 0, 0, 0);
            }
#pragma unroll
        for (int mt = 0; mt < 5; ++mt)
#pragma unroll
            for (int q = 0; q < 4; ++q) {
                int row = mt * 16 + lg * 4 + q;
                int col = w * 16 + lr;
                smZ[row * 68 + col] = accS[mt][q];
            }
    }
    __syncthreads();

    // ---- FSMN epilogue: 2 adjacent d per thread, 8 rows each ----
    {
        const int dp = (tid & 31) * 2;
        const int r0 = (tid >> 5) * 8;
        float wla[10], wlb[10];
#pragma unroll
        for (int k = 0; k < 10; ++k) {
            float2 wv = *reinterpret_cast<const float2*>(wl + k * 64 + dp);
            wla[k] = wv.x; wlb[k] = wv.y;
        }
        float2 wrv = *reinterpret_cast<const float2*>(wr + dp);
        float2 zw[11];                     // z[t-9..t+1] for t = t0+r0
#pragma unroll
        for (int j = 0; j < 11; ++j) {
            int tt = t0 + r0 - 9 + j;
            zw[j] = (tt >= 0 && tt < TLEN)
                  ? *reinterpret_cast<const float2*>(smZ + (r0 + 1 + j) * 68 + dp)
                  : make_float2(0.f, 0.f);
        }
#pragma unroll
        for (int i = 0; i < 8; ++i) {
            int ro = r0 + i, t = t0 + ro;
            float a0 = zw[9].x, a1 = zw[9].y;
#pragma unroll
            for (int k = 0; k < 10; ++k) { a0 += wla[k] * zw[k].x; a1 += wlb[k] * zw[k].y; }
            a0 += wrv.x * zw[10].x; a1 += wrv.y * zw[10].y;
            if (HAS_RES) {
                int rowX = ro + 10;        // residual = staged input row
                ushort2 h = *reinterpret_cast<const ushort2*>(
                    smXb + ((rowX * 128 + dp * 2) ^ ((rowX & 7) << 4)));
                a0 += b2f(h.x); a1 += b2f(h.y);
            }
            ushort2 o; o.x = f2b(a0); o.y = f2b(a1);
            *reinterpret_cast<ushort2*>(Hout + (size_t)(s * TLEN + t) * 64 + dp) = o;
            if (i < 7) {
#pragma unroll
                for (int j = 0; j < 10; ++j) zw[j] = zw[j + 1];
                int tt = t + 2;
                zw[10] = (tt < TLEN)
                       ? *reinterpret_cast<const float2*>(smZ + (ro + 12) * 68 + dp)
                       : make_float2(0.f, 0.f);
            }
        }
    }
}

// ---- final: out[b,t,:] = (max_c relu(H[b,c,t,:] @ We2 + be2)) @ Wd + bd ----
// Block: 16 t of one b. A rows m = c*16 + tl -> fragment mt == channel, so
// max over c is an elementwise max over the 4 A-fragments.
__global__ __launch_bounds__(256) void final_mfma(
    const ushort* __restrict__ H, const ushort* __restrict__ We2T,
    const float* __restrict__ be2, const float* __restrict__ Wd,
    const float* __restrict__ bd, float* __restrict__ out)
{
    __shared__ char smA[64 * 128];        // [c*16+tl][64] bf16, src-swizzled
    __shared__ float Ml[16][132];
    const int tid = threadIdx.x;
    const int ln  = tid & 63;
    const int w   = tid >> 6;
    const int lr  = ln & 15;
    const int lg  = ln >> 4;
    const int b   = blockIdx.x >> 7;
    const int t0  = (blockIdx.x & 127) * 16;

    // stage: wave w loads channel c=w (16 rows x 128B), 2 calls of 8 rows
#pragma unroll
    for (int it = 0; it < 2; ++it) {
        int r0 = w * 16 + it * 8;
        int tl = it * 8 + (ln >> 3);
        int m  = r0 + (ln >> 3);
        int sslot = (ln & 7) ^ (m & 7);
        gload16(smA + r0 * 128,
                H + (size_t)((b * 4 + w) * TLEN + t0 + tl) * 64 + sslot * 8);
    }
    __syncthreads();

    {
        bf16x8 bW[2][2];
#pragma unroll
        for (int nt = 0; nt < 2; ++nt)
#pragma unroll
            for (int kc = 0; kc < 2; ++kc) {
                int n = w * 32 + nt * 16 + lr;
                bW[nt][kc] = *reinterpret_cast<const bf16x8*>(
                    We2T + n * 64 + kc * 32 + lg * 8);
            }
        f32x4 acc[4][2];
#pragma unroll
        for (int mt = 0; mt < 4; ++mt)
#pragma unroll
            for (int nt = 0; nt < 2; ++nt) acc[mt][nt] = (f32x4){0.f, 0.f, 0.f, 0.f};
#pragma unroll
        for (int kc = 0; kc < 2; ++kc) {
            bf16x8 a[4];
#pragma unroll
            for (int mt = 0; mt < 4; ++mt) {
                int m = mt * 16 + lr;
                int off = (m * 128 + kc * 64 + lg * 16) ^ ((m & 7) << 4);
                a[mt] = *reinterpret_cast<const bf16x8*>(smA + off);
            }
#pragma unroll
            for (int mt = 0; mt < 4; ++mt)
#pragma unroll
                for (int nt = 0; nt < 2; ++nt)
                    acc[mt][nt] = __builtin_amdgcn_mfma_f32_16x16x32_bf16(
                        a[mt], bW[nt][kc], acc[mt][nt], 0, 0, 0);
        }
        // max over channel (mt), + bias, relu
#pragma unroll
        for (int nt = 0; nt < 2; ++nt) {
            float bb = be2[w * 32 + nt * 16 + lr];
#pragma unroll
            for (int q = 0; q < 4; ++q) {
                float m01 = fmaxf(acc[0][nt][q], acc[1][nt][q]);
                float m23 = fmaxf(acc[2][nt][q], acc[3][nt][q]);
                Ml[lg * 4 + q][w * 32 + nt * 16 + lr] =
                    fmaxf(fmaxf(m01, m23) + bb, 0.f);
            }
        }
    }
    __syncthreads();

    // decode: 80 threads, 4-way partial sums
    if (tid < 80) {
        int t = tid / 5, q = tid - t * 5;
        float a0 = 0.f, a1 = 0.f, a2 = 0.f, a3 = 0.f;
        for (int j = 0; j < 128; j += 4) {
            a0 += Ml[t][j]     * Wd[j * 5 + q];
            a1 += Ml[t][j + 1] * Wd[(j + 1) * 5 + q];
            a2 += Ml[t][j + 2] * Wd[(j + 2) * 5 + q];
            a3 += Ml[t][j + 3] * Wd[(j + 3) * 5 + q];
        }
        out[(size_t)(b * TLEN + t0 + t) * 5 + q] = a0 + a1 + a2 + a3 + bd[q];
    }
}

extern "C" void kernel_launch(void* const* d_in, const int* in_sizes, int n_in,
                              void* d_out, int out_size, void* d_ws, size_t ws_size,
                              hipStream_t stream) {
    const float* x   = (const float*)d_in[0];
    const float* We0 = (const float*)d_in[1];
    const float* be0 = (const float*)d_in[2];
    const float* Ws0 = (const float*)d_in[3];
    const float* wl0 = (const float*)d_in[4];
    const float* wr0 = (const float*)d_in[5];
    const float* We  = (const float*)d_in[6];
    const float* be  = (const float*)d_in[7];
    const float* Ws  = (const float*)d_in[8];
    const float* wl  = (const float*)d_in[9];
    const float* wr  = (const float*)d_in[10];
    const float* We2 = (const float*)d_in[11];
    const float* be2 = (const float*)d_in[12];
    const float* Wd  = (const float*)d_in[13];
    const float* bd  = (const float*)d_in[14];

    ushort* H0 = (ushort*)d_ws;                               // 33.5 MB
    ushort* H1 = H0 + (size_t)SEQS * TLEN * 64;               // 33.5 MB
    ushort* wbuf = H1 + (size_t)SEQS * TLEN * 64;             // 196 KB (ws has >=134MB)

    prep_k<<<384, 256, 0, stream>>>(We0, Ws0, We, Ws, We2, wbuf);

    dim3 gU(TLEN / 64, SEQS);
    unit_fused<128, true, false><<<gU, 256, 0, stream>>>(
        x, wbuf, be0, wbuf + 16384, wl0, wr0, H0);

    ushort* cur = H0;
    ushort* nxt = H1;
    for (int l = 0; l < 4; ++l) {
        const ushort* WeTl = wbuf + 24576 + l * 16384;
        const ushort* WsTl = WeTl + 8192;
        unit_fused<64, false, true><<<gU, 256, 0, stream>>>(
            cur, WeTl, be + l * 128, WsTl, wl + l * 640, wr + l * 64, nxt);
        ushort* tmp = cur; cur = nxt; nxt = tmp;
    }
    // after 4 swaps cur == H0

    final_mfma<<<32 * 128, 256, 0, stream>>>(cur, wbuf + 90112, be2, Wd, bd,
                                             (float*)d_out);
}

// Round 4
// 226.046 us; speedup vs baseline: 6.2446x; 1.0593x over previous
//
#include <hip/hip_runtime.h>
#include <hip/hip_bf16.h>

// FSMNSeleNetV3 — round 4: VALU-count reduction + occupancy 4 blocks/CU.
//   * v_cvt_pk_bf16_f32 for all f32->bf16 pair packing (E, H, unit0 stage)
//   * E stored as packed pairs; WsT k-rows pre-permuted to match (exact)
//   * v_pk_fma_f32 for the 11-tap FSMN epilogue
//   * LDS = 40960 B exactly (X/E aliased + swizzled Z) -> 4 blocks/CU
//   * residual re-read from global (ping-pong buffers make it safe)
//   * final decode via transposed WdT + float4
// d_ws: H0 (33.5MB) + H1 (33.5MB) + wbuf (192KB bf16 weights) + WdT (2.5KB f32).

#define TLEN 2048
#define SEQS 128

typedef __attribute__((ext_vector_type(8))) short bf16x8;
typedef __attribute__((ext_vector_type(4))) float f32x4;
typedef __attribute__((ext_vector_type(2))) float f32x2;

__device__ __forceinline__ ushort f2b(float f) {
    unsigned u = __builtin_bit_cast(unsigned, f);
    return (ushort)((u + 0x7fffu + ((u >> 16) & 1u)) >> 16);  // RNE
}
__device__ __forceinline__ float b2f(ushort u) {
    unsigned v = ((unsigned)u) << 16;
    return __builtin_bit_cast(float, v);
}
__device__ __forceinline__ unsigned cvtpk(float lo, float hi) {  // RNE pack
    unsigned r;
    asm("v_cvt_pk_bf16_f32 %0, %1, %2" : "=v"(r) : "v"(lo), "v"(hi));
    return r;
}
__device__ __forceinline__ f32x2 pkfma(f32x2 a, f32x2 b, f32x2 c) {
    f32x2 d;
    asm("v_pk_fma_f32 %0, %1, %2, %3" : "=v"(d) : "v"(a), "v"(b), "v"(c));
    return d;
}
__device__ __forceinline__ void gload16(void* lds, const void* g) {
    __builtin_amdgcn_global_load_lds(
        (const __attribute__((address_space(1))) unsigned*)g,
        (__attribute__((address_space(3))) unsigned*)lds, 16, 0, 0);
}

// storage k' -> source k for the E pair-packing permutation:
// k' = 32a + 2r + nb  <->  k = 32a + 16nb + r
__device__ __forceinline__ int kperm(int kp) {
    return (kp & ~31) | ((kp & 1) << 4) | ((kp & 31) >> 1);
}

// ---- weight prep ----
// wbuf (ushort): WeT0 [128][128] @0 ; WsT0p [64][128] @16384
//   l=0..3: WeTl [128][64] @24576+l*16384 ; WsTlp [64][128] @+8192
//   We2T [128][64] @90112  (total 98304)
// wdtf (float): WdT [5][128] @wbuf+98304
__global__ __launch_bounds__(256) void prep_k(
    const float* __restrict__ We0, const float* __restrict__ Ws0,
    const float* __restrict__ We,  const float* __restrict__ Ws,
    const float* __restrict__ We2, const float* __restrict__ Wd,
    ushort* __restrict__ wbuf, float* __restrict__ wdtf)
{
    int idx = blockIdx.x * 256 + threadIdx.x;
    if (idx >= 98944) return;
    if (idx >= 98304) {                       // WdT (f32, transposed)
        int i = idx - 98304;
        wdtf[i] = Wd[(i & 127) * 5 + (i >> 7)];
        return;
    }
    float v;
    if (idx < 16384) {                        // WeT0
        int n = idx >> 7, k = idx & 127;
        v = (k < 120) ? We0[k * 128 + n] : 0.f;
    } else if (idx < 24576) {                 // WsT0 (k-permuted)
        int i = idx - 16384;
        int n = i >> 7, k = kperm(i & 127);
        v = Ws0[k * 64 + n];
    } else if (idx < 90112) {
        int i = idx - 24576;
        int l = i >> 14, j = i & 16383;
        if (j < 8192) {                       // WeTl
            int n = j >> 6, k = j & 63;
            v = We[l * 8192 + k * 128 + n];
        } else {                              // WsTl (k-permuted)
            int j2 = j - 8192;
            int n = j2 >> 7, k = kperm(j2 & 127);
            v = Ws[l * 8192 + k * 64 + n];
        }
    } else {                                  // We2T
        int i = idx - 90112;
        int n = i >> 6, k = i & 63;
        v = We2[k * 128 + n];
    }
    wbuf[idx] = f2b(v);
}

// ---- fused unit kernel: 64 output rows of sequence s, stages rows t0-10..t0+69 ----
// LDS (40960 B = 4 blocks/CU):
//   region A (20480): X [80][KDIM] bf16 (swz (row&7)<<4), ALIASED by E [80][128]
//                     packed-pairs bf16 (same swz) after the mid-expand barrier.
//   region B (20480): Z [80][64] f32, swz (row&15)<<3.
template <int KDIM, bool X0, bool HAS_RES>
__global__ __launch_bounds__(256, 4) void unit_fused(
    const void* __restrict__ inv, const ushort* __restrict__ WeT,
    const float* __restrict__ be, const ushort* __restrict__ WsT,
    const float* __restrict__ wl, const float* __restrict__ wr,
    ushort* __restrict__ Hout)
{
    __shared__ char smraw[40960];
    char* smA = smraw;
    char* smB = smraw + 20480;

    const int tid = threadIdx.x;
    const int s   = blockIdx.y;
    const int t0  = blockIdx.x * 64;
    const int ln  = tid & 63;
    const int w   = tid >> 6;
    const int lr  = ln & 15;
    const int lg  = ln >> 4;

    // ---- stage X into region A ----
    if constexpr (X0) {
        const float* in = (const float*)inv;
        const int bq = s >> 2, cq = s & 3;
        for (int i = tid; i < 80 * 16; i += 256) {
            int r = i >> 4, s16 = i & 15;
            int t = t0 - 10 + r;
            float4 v0 = make_float4(0.f, 0.f, 0.f, 0.f), v1 = v0;
            if (t >= 0 && t < TLEN && s16 < 15) {
                int fb = ((bq * TLEN + t) * 4 + cq) * 120 + s16 * 8;
                v0 = *reinterpret_cast<const float4*>(in + fb);
                v1 = *reinterpret_cast<const float4*>(in + fb + 4);
            }
            uint4 p;
            p.x = cvtpk(v0.x, v0.y); p.y = cvtpk(v0.z, v0.w);
            p.z = cvtpk(v1.x, v1.y); p.w = cvtpk(v1.z, v1.w);
            int off = (r * 256 + s16 * 16) ^ ((r & 7) << 4);
            *reinterpret_cast<uint4*>(smA + off) = p;
        }
    } else {
        const ushort* Hin = (const ushort*)inv;
        bf16x8 zv = {0, 0, 0, 0, 0, 0, 0, 0};
        if (t0 == 0)
            for (int i = tid; i < 80; i += 256)
                *reinterpret_cast<bf16x8*>(smA + i * 16) = zv;
        if (t0 == TLEN - 64)
            for (int i = tid; i < 48; i += 256)
                *reinterpret_cast<bf16x8*>(smA + (74 * 8 + i) * 16) = zv;
#pragma unroll
        for (int it = 0; it < 3; ++it) {
            int r0 = it * 32 + w * 8;
            if (r0 < 80) {
                int row = r0 + (ln >> 3);
                int t   = t0 - 10 + row;
                int sslot = (ln & 7) ^ (row & 7);
                if (t >= 0 && t < TLEN)
                    gload16(smA + r0 * 128,
                            Hin + (size_t)(s * TLEN + t) * 64 + sslot * 8);
            }
        }
    }
    __syncthreads();

    // ---- expand accumulate: relu(X @ We + be); wave w: cols w*32..+32 ----
    constexpr int KC = KDIM / 32;
    f32x4 accE[5][2];
    {
        bf16x8 bE[2][KC];
#pragma unroll
        for (int nt = 0; nt < 2; ++nt)
#pragma unroll
            for (int kc = 0; kc < KC; ++kc) {
                int n = w * 32 + nt * 16 + lr;
                bE[nt][kc] = *reinterpret_cast<const bf16x8*>(
                    WeT + n * KDIM + kc * 32 + lg * 8);
            }
#pragma unroll
        for (int mt = 0; mt < 5; ++mt)
#pragma unroll
            for (int nt = 0; nt < 2; ++nt) accE[mt][nt] = (f32x4){0.f, 0.f, 0.f, 0.f};
#pragma unroll
        for (int kc = 0; kc < KC; ++kc) {
            bf16x8 a[5];
#pragma unroll
            for (int mt = 0; mt < 5; ++mt) {
                int row = mt * 16 + lr;
                int off = (row * (KDIM * 2) + kc * 64 + lg * 16) ^ ((row & 7) << 4);
                a[mt] = *reinterpret_cast<const bf16x8*>(smA + off);
            }
#pragma unroll
            for (int mt = 0; mt < 5; ++mt)
#pragma unroll
                for (int nt = 0; nt < 2; ++nt)
                    accE[mt][nt] = __builtin_amdgcn_mfma_f32_16x16x32_bf16(
                        a[mt], bE[nt][kc], accE[mt][nt], 0, 0, 0);
        }
    }
    __syncthreads();   // ALL waves done reading X -> safe to overwrite with E

    // ---- E store: packed pairs (col, col+16) as one u32, b32 writes ----
    {
        float b0 = be[w * 32 + lr];
        float b1 = be[w * 32 + 16 + lr];
#pragma unroll
        for (int mt = 0; mt < 5; ++mt)
#pragma unroll
            for (int q = 0; q < 4; ++q) {
                int row = mt * 16 + lg * 4 + q;
                float v0 = fmaxf(accE[mt][0][q] + b0, 0.f);
                float v1 = fmaxf(accE[mt][1][q] + b1, 0.f);
                int off = (row * 256 + w * 64 + lr * 4) ^ ((row & 7) << 4);
                *reinterpret_cast<unsigned*>(smA + off) = cvtpk(v0, v1);
            }
    }
    __syncthreads();

    // ---- shrink: Z[80][64] = E @ WsT_perm; wave w: cols w*16..+16 ----
    {
        bf16x8 bS[4];
#pragma unroll
        for (int kc = 0; kc < 4; ++kc) {
            int n = w * 16 + lr;
            bS[kc] = *reinterpret_cast<const bf16x8*>(WsT + n * 128 + kc * 32 + lg * 8);
        }
        f32x4 accS[5];
#pragma unroll
        for (int mt = 0; mt < 5; ++mt) accS[mt] = (f32x4){0.f, 0.f, 0.f, 0.f};
#pragma unroll
        for (int kc = 0; kc < 4; ++kc)
#pragma unroll
            for (int mt = 0; mt < 5; ++mt) {
                int row = mt * 16 + lr;
                int off = (row * 256 + kc * 64 + lg * 16) ^ ((row & 7) << 4);
                bf16x8 a = *reinterpret_cast<const bf16x8*>(smA + off);
                accS[mt] = __builtin_amdgcn_mfma_f32_16x16x32_bf16(
                    a, bS[kc], accS[mt], 0, 0, 0);
            }
#pragma unroll
        for (int mt = 0; mt < 5; ++mt)
#pragma unroll
            for (int q = 0; q < 4; ++q) {
                int row = mt * 16 + lg * 4 + q;
                int off = (row * 256 + (w * 16 + lr) * 4) ^ ((row & 15) << 3);
                *reinterpret_cast<float*>(smB + off) = accS[mt][q];
            }
    }
    __syncthreads();

    // ---- FSMN epilogue (pk_fma): 2 adjacent d per thread, 8 rows each ----
    {
        const int dp = (tid & 31) * 2;
        const int r0 = (tid >> 5) * 8;
        f32x2 wl2[10];
#pragma unroll
        for (int k = 0; k < 10; ++k)
            wl2[k] = *reinterpret_cast<const f32x2*>(wl + k * 64 + dp);
        f32x2 wr2 = *reinterpret_cast<const f32x2*>(wr + dp);

        ushort2 rs[8];
        if (HAS_RES) {
            const ushort* Hin = (const ushort*)inv;
#pragma unroll
            for (int i = 0; i < 8; ++i)
                rs[i] = *reinterpret_cast<const ushort2*>(
                    Hin + (size_t)(s * TLEN + t0 + r0 + i) * 64 + dp);
        }

        f32x2 zw[11];                       // z[t-9..t+1] for t = t0+r0
#pragma unroll
        for (int j = 0; j < 11; ++j) {
            int tt = t0 + r0 - 9 + j;
            int r  = r0 + 1 + j;
            zw[j] = (tt >= 0 && tt < TLEN)
                  ? *reinterpret_cast<const f32x2*>(
                        smB + ((r * 256 + dp * 4) ^ ((r & 15) << 3)))
                  : (f32x2){0.f, 0.f};
        }
#pragma unroll
        for (int i = 0; i < 8; ++i) {
            int ro = r0 + i, t = t0 + ro;
            f32x2 acc = zw[9];
#pragma unroll
            for (int k = 0; k < 10; ++k) acc = pkfma(wl2[k], zw[k], acc);
            acc = pkfma(wr2, zw[10], acc);
            float a0 = acc[0], a1 = acc[1];
            if (HAS_RES) { a0 += b2f(rs[i].x); a1 += b2f(rs[i].y); }
            *reinterpret_cast<unsigned*>(
                Hout + (size_t)(s * TLEN + t) * 64 + dp) = cvtpk(a0, a1);
            if (i < 7) {
#pragma unroll
                for (int j = 0; j < 10; ++j) zw[j] = zw[j + 1];
                int tt = t + 2;
                int r  = ro + 12;
                zw[10] = (tt < TLEN)
                       ? *reinterpret_cast<const f32x2*>(
                             smB + ((r * 256 + dp * 4) ^ ((r & 15) << 3)))
                       : (f32x2){0.f, 0.f};
            }
        }
    }
}

// ---- final: out[b,t,:] = (max_c relu(H[b,c,t,:] @ We2 + be2)) @ Wd + bd ----
__global__ __launch_bounds__(256) void final_mfma(
    const ushort* __restrict__ H, const ushort* __restrict__ We2T,
    const float* __restrict__ be2, const float* __restrict__ WdT,
    const float* __restrict__ bd, float* __restrict__ out)
{
    __shared__ char smA[64 * 128];        // [c*16+tl][64] bf16, src-swizzled
    __shared__ float Ml[16][132];
    const int tid = threadIdx.x;
    const int ln  = tid & 63;
    const int w   = tid >> 6;
    const int lr  = ln & 15;
    const int lg  = ln >> 4;
    const int b   = blockIdx.x >> 7;
    const int t0  = (blockIdx.x & 127) * 16;

#pragma unroll
    for (int it = 0; it < 2; ++it) {
        int r0 = w * 16 + it * 8;
        int tl = it * 8 + (ln >> 3);
        int m  = r0 + (ln >> 3);
        int sslot = (ln & 7) ^ (m & 7);
        gload16(smA + r0 * 128,
                H + (size_t)((b * 4 + w) * TLEN + t0 + tl) * 64 + sslot * 8);
    }
    __syncthreads();

    {
        bf16x8 bW[2][2];
#pragma unroll
        for (int nt = 0; nt < 2; ++nt)
#pragma unroll
            for (int kc = 0; kc < 2; ++kc) {
                int n = w * 32 + nt * 16 + lr;
                bW[nt][kc] = *reinterpret_cast<const bf16x8*>(
                    We2T + n * 64 + kc * 32 + lg * 8);
            }
        f32x4 acc[4][2];
#pragma unroll
        for (int mt = 0; mt < 4; ++mt)
#pragma unroll
            for (int nt = 0; nt < 2; ++nt) acc[mt][nt] = (f32x4){0.f, 0.f, 0.f, 0.f};
#pragma unroll
        for (int kc = 0; kc < 2; ++kc) {
            bf16x8 a[4];
#pragma unroll
            for (int mt = 0; mt < 4; ++mt) {
                int m = mt * 16 + lr;
                int off = (m * 128 + kc * 64 + lg * 16) ^ ((m & 7) << 4);
                a[mt] = *reinterpret_cast<const bf16x8*>(smA + off);
            }
#pragma unroll
            for (int mt = 0; mt < 4; ++mt)
#pragma unroll
                for (int nt = 0; nt < 2; ++nt)
                    acc[mt][nt] = __builtin_amdgcn_mfma_f32_16x16x32_bf16(
                        a[mt], bW[nt][kc], acc[mt][nt], 0, 0, 0);
        }
#pragma unroll
        for (int nt = 0; nt < 2; ++nt) {
            float bb = be2[w * 32 + nt * 16 + lr];
#pragma unroll
            for (int q = 0; q < 4; ++q) {
                float m01 = fmaxf(acc[0][nt][q], acc[1][nt][q]);
                float m23 = fmaxf(acc[2][nt][q], acc[3][nt][q]);
                Ml[lg * 4 + q][w * 32 + nt * 16 + lr] =
                    fmaxf(fmaxf(m01, m23) + bb, 0.f);
            }
        }
    }
    __syncthreads();

    if (tid < 80) {
        int t = tid / 5, q = tid - t * 5;
        const float4* wq = reinterpret_cast<const float4*>(WdT + q * 128);
        const float4* mq = reinterpret_cast<const float4*>(&Ml[t][0]);
        float s0 = 0.f, s1 = 0.f, s2 = 0.f, s3 = 0.f;
#pragma unroll 4
        for (int j = 0; j < 32; ++j) {
            float4 m = mq[j], wv = wq[j];
            s0 += m.x * wv.x; s1 += m.y * wv.y;
            s2 += m.z * wv.z; s3 += m.w * wv.w;
        }
        out[(size_t)(b * TLEN + t0 + t) * 5 + q] = s0 + s1 + s2 + s3 + bd[q];
    }
}

extern "C" void kernel_launch(void* const* d_in, const int* in_sizes, int n_in,
                              void* d_out, int out_size, void* d_ws, size_t ws_size,
                              hipStream_t stream) {
    const float* x   = (const float*)d_in[0];
    const float* We0 = (const float*)d_in[1];
    const float* be0 = (const float*)d_in[2];
    const float* Ws0 = (const float*)d_in[3];
    const float* wl0 = (const float*)d_in[4];
    const float* wr0 = (const float*)d_in[5];
    const float* We  = (const float*)d_in[6];
    const float* be  = (const float*)d_in[7];
    const float* Ws  = (const float*)d_in[8];
    const float* wl  = (const float*)d_in[9];
    const float* wr  = (const float*)d_in[10];
    const float* We2 = (const float*)d_in[11];
    const float* be2 = (const float*)d_in[12];
    const float* Wd  = (const float*)d_in[13];
    const float* bd  = (const float*)d_in[14];

    ushort* H0 = (ushort*)d_ws;                               // 33.5 MB
    ushort* H1 = H0 + (size_t)SEQS * TLEN * 64;               // 33.5 MB
    ushort* wbuf = H1 + (size_t)SEQS * TLEN * 64;             // 192 KB
    float* wdtf = (float*)(wbuf + 98304);                     // 2.5 KB

    prep_k<<<387, 256, 0, stream>>>(We0, Ws0, We, Ws, We2, Wd, wbuf, wdtf);

    dim3 gU(TLEN / 64, SEQS);
    unit_fused<128, true, false><<<gU, 256, 0, stream>>>(
        x, wbuf, be0, wbuf + 16384, wl0, wr0, H0);

    ushort* cur = H0;
    ushort* nxt = H1;
    for (int l = 0; l < 4; ++l) {
        const ushort* WeTl = wbuf + 24576 + l * 16384;
        const ushort* WsTl = WeTl + 8192;
        unit_fused<64, false, true><<<gU, 256, 0, stream>>>(
            cur, WeTl, be + l * 128, WsTl, wl + l * 640, wr + l * 64, nxt);
        ushort* tmp = cur; cur = nxt; nxt = tmp;
    }
    // after 4 swaps cur == H0

    final_mfma<<<32 * 128, 256, 0, stream>>>(cur, wbuf + 90112, be2, wdtf, bd,
                                             (float*)d_out);
}